// Round 8
// baseline (782.976 us; speedup 1.0000x reference)
//
#include <hip/hip_runtime.h>
#include <math.h>

#define NEG_SLOPE 0.2f

// ---------------------------------------------------------------- CSR build
__global__ void deg_count_kernel(const int* __restrict__ dst, int* __restrict__ deg, int E){
  int e = blockIdx.x * blockDim.x + threadIdx.x;
  if (e < E) atomicAdd(&deg[dst[e]], 1);
}

__global__ void base_assign_kernel(const int* __restrict__ deg, int* __restrict__ base,
                                   int* __restrict__ counter, int N){
  int n = blockIdx.x * blockDim.x + threadIdx.x;
  if (n < N) base[n] = atomicAdd(counter, deg[n]);
}

__global__ void fill_kernel(const int* __restrict__ ei, const float* __restrict__ ea,
                            const int* __restrict__ base, int* __restrict__ pos,
                            int2* __restrict__ csr_pack, int E){
  int e = blockIdx.x * blockDim.x + threadIdx.x;
  if (e >= E) return;
  int s = ei[e], d = ei[E + e];
  int p = atomicAdd(&pos[d], 1);
  csr_pack[base[d] + p] = make_int2(s, __float_as_int(ea[e]));
}

// ---------------------------------------------------------------- barrier-free dual GEMM
// Wave = 64 output cols of one W (blockIdx.y picks W1/W2 and col-half); lane holds the
// ENTIRE W column in VGPRs (K regs, loaded once, coalesced across lanes). Rows stream
// in 8/32-row groups through wave-private LDS (no __syncthreads anywhere): coalesced
// global float4 -> LDS, then uniform-address ds_read (HW broadcast, conflict-free)
// feeds per-lane FMAs into 4 partial accumulators.
template<int M, int K, int RPW>
__global__ __launch_bounds__(256, 3) void gemm_cols_kernel(
    const float* __restrict__ X,
    const float* __restrict__ W1, const float* __restrict__ b1,
    const float* __restrict__ W2, const float* __restrict__ b2,
    float* __restrict__ Y1, float* __restrict__ Y2, int N)
{
  constexpr int GPM = M / 64;                 // col-groups per matrix (2 or 1)
  constexpr int GR  = (K >= 64) ? 8 : 32;     // rows per staging group
  constexpr int KR  = ((K + 3) / 4) * 4;
  __shared__ float xsh[4][GR * K + 4];

  int g = blockIdx.y;                         // [0, 2*GPM)
  const float* W  = (g < GPM) ? W1 : W2;
  const float* bs = (g < GPM) ? b1 : b2;
  float*       Y  = (g < GPM) ? Y1 : Y2;
  int c0 = (g % GPM) * 64;

  int lane = threadIdx.x & 63;
  int wid  = threadIdx.x >> 6;
  int chunk = blockIdx.x * 4 + wid;
  long r0 = (long)chunk * RPW;
  if (r0 >= N) return;
  int rcnt = (int)min((long)RPW, (long)N - r0);

  int c = c0 + lane;
  float wreg[KR];
  #pragma unroll
  for (int k = 0; k < KR; k++)
    wreg[k] = (k < K) ? W[(long)k * M + c] : 0.f;
  float bias = bs[c];

  float* xs = xsh[wid];

  for (int gb = 0; gb < rcnt; gb += GR){
    int gn = rcnt - gb; if (gn > GR) gn = GR;
    const float* xg = X + (r0 + gb) * K;
    if constexpr (K % 4 == 0){
      constexpr int NF4 = GR * K / 4;        // float4 slots per full group
      int lim = gn * (K / 4);
      #pragma unroll
      for (int i = 0; i < NF4 / 64; i++){
        int idx = lane + i * 64;
        if (idx < lim){
          float4 v = *(const float4*)(xg + 4 * idx);
          *(float4*)&xs[4 * idx] = v;
        }
      }
    } else {
      int lim = gn * K;
      constexpr int ND = (GR * K + 63) / 64;
      #pragma unroll
      for (int i = 0; i < ND; i++){
        int idx = lane + i * 64;
        if (idx < lim) xs[idx] = xg[idx];
      }
    }
    // same-wave LDS ordering (lgkmcnt) — no barrier needed
    for (int j = 0; j < gn; j++){
      const float* xrow = xs + j * K;
      float a0 = 0.f, a1 = 0.f, a2 = 0.f, a3 = 0.f;
      if constexpr (K % 4 == 0){
        #pragma unroll
        for (int k4 = 0; k4 < K / 4; k4++){
          float4 xv = *(const float4*)(xrow + 4 * k4);   // uniform addr -> broadcast
          a0 = fmaf(xv.x, wreg[4*k4+0], a0);
          a1 = fmaf(xv.y, wreg[4*k4+1], a1);
          a2 = fmaf(xv.z, wreg[4*k4+2], a2);
          a3 = fmaf(xv.w, wreg[4*k4+3], a3);
        }
      } else {
        #pragma unroll
        for (int k = 0; k < K; k++){
          float xv = xrow[k];
          if ((k & 3) == 0)      a0 = fmaf(xv, wreg[k], a0);
          else if ((k & 3) == 1) a1 = fmaf(xv, wreg[k], a1);
          else if ((k & 3) == 2) a2 = fmaf(xv, wreg[k], a2);
          else                   a3 = fmaf(xv, wreg[k], a3);
        }
      }
      Y[(r0 + gb + j) * M + c] = ((a0 + a1) + (a2 + a3)) + bias;
    }
  }
}

// ---------------------------------------------------------------- fused edge softmax + aggregation
// (unchanged) One wave per dst node, lane owns 8 contiguous channels,
// contiguous row reads, 32-bit saddr offsets, no-max softmax, optional fused linear.
template<int C>
__global__ __launch_bounds__(512) void agg_kernel(
    const float* __restrict__ xl, const float* __restrict__ xr,
    const int* __restrict__ base, const int* __restrict__ deg,
    const int2* __restrict__ csr_pack,
    const float* __restrict__ We, const float* __restrict__ att,
    const float* __restrict__ bias, float* __restrict__ hout,
    const float* __restrict__ Wlin, const float* __restrict__ blin,
    float* __restrict__ outF, int N, int do_elu)
{
  constexpr int HC  = 8 * C;
  constexpr int LPE = HC / 8;
  constexpr int ES  = 64 / LPE;
  constexpr int NP  = (LPE == 16) ? 4 : 2;
  constexpr int B   = ES * NP;
  constexpr int SH  = (HC == 128) ? 9 : 8;
  constexpr int HR  = C / 8;

  int lane = threadIdx.x & 63;
  int wv   = blockIdx.x * (blockDim.x >> 6) + (threadIdx.x >> 6);
  int nwv  = gridDim.x * (blockDim.x >> 6);
  int slot = lane / LPE;
  int hl   = lane % LPE;
  unsigned cb = (unsigned)hl * 32u;

  const char* xlb = (const char*)xl;
  const char* xrb = (const char*)xr;

  float4 attA = *(const float4*)((const char*)att + cb);
  float4 attB = *(const float4*)((const char*)att + cb + 16);
  float4 weA  = *(const float4*)((const char*)We  + cb);
  float4 weB  = *(const float4*)((const char*)We  + cb + 16);

  for (int n = wv; n < N; n += nwv){
    unsigned nb = ((unsigned)n << SH) + cb;
    float4 xrA = *(const float4*)(xrb + nb);
    float4 xrB = *(const float4*)(xrb + nb + 16);
    float4 accA = {0.f,0.f,0.f,0.f}, accB = {0.f,0.f,0.f,0.f};
    float lrun = 0.f;
    int s0 = base[n], end = s0 + deg[n];

    for (int s = s0; s < end; s += B){
      int2 pk[NP]; bool val[NP];
      #pragma unroll
      for (int t = 0; t < NP; t++){
        int idx = s + t * ES + slot;
        val[t] = idx < end;
        pk[t]  = csr_pack[val[t] ? idx : s0];
      }
      float4 rA[NP], rB[NP];
      #pragma unroll
      for (int t = 0; t < NP; t++){
        unsigned ro = ((unsigned)pk[t].x << SH) + cb;
        rA[t] = *(const float4*)(xlb + ro);
        rB[t] = *(const float4*)(xlb + ro + 16);
      }
      #pragma unroll
      for (int t = 0; t < NP; t++){
        float eav = __int_as_float(pk[t].y);
        float t0 = rA[t].x + xrA.x + eav * weA.x;
        float t1 = rA[t].y + xrA.y + eav * weA.y;
        float t2 = rA[t].z + xrA.z + eav * weA.z;
        float t3 = rA[t].w + xrA.w + eav * weA.w;
        float t4 = rB[t].x + xrB.x + eav * weB.x;
        float t5 = rB[t].y + xrB.y + eav * weB.y;
        float t6 = rB[t].z + xrB.z + eav * weB.z;
        float t7 = rB[t].w + xrB.w + eav * weB.w;
        float m0 = fmaxf(t0,0.f) + NEG_SLOPE * fminf(t0,0.f);
        float m1 = fmaxf(t1,0.f) + NEG_SLOPE * fminf(t1,0.f);
        float m2 = fmaxf(t2,0.f) + NEG_SLOPE * fminf(t2,0.f);
        float m3 = fmaxf(t3,0.f) + NEG_SLOPE * fminf(t3,0.f);
        float m4 = fmaxf(t4,0.f) + NEG_SLOPE * fminf(t4,0.f);
        float m5 = fmaxf(t5,0.f) + NEG_SLOPE * fminf(t5,0.f);
        float m6 = fmaxf(t6,0.f) + NEG_SLOPE * fminf(t6,0.f);
        float m7 = fmaxf(t7,0.f) + NEG_SLOPE * fminf(t7,0.f);
        float p = ((m0*attA.x + m1*attA.y) + (m2*attA.z + m3*attA.w))
                + ((m4*attB.x + m5*attB.y) + (m6*attB.z + m7*attB.w));
        #pragma unroll
        for (int o = 1; o < HR; o <<= 1) p += __shfl_xor(p, o);
        float pe = val[t] ? __expf(p) : 0.f;
        lrun += pe;
        accA.x += pe * rA[t].x; accA.y += pe * rA[t].y;
        accA.z += pe * rA[t].z; accA.w += pe * rA[t].w;
        accB.x += pe * rB[t].x; accB.y += pe * rB[t].y;
        accB.z += pe * rB[t].z; accB.w += pe * rB[t].w;
      }
    }
    #pragma unroll
    for (int o = LPE; o < 64; o <<= 1){
      lrun  += __shfl_xor(lrun, o);
      accA.x += __shfl_xor(accA.x, o); accA.y += __shfl_xor(accA.y, o);
      accA.z += __shfl_xor(accA.z, o); accA.w += __shfl_xor(accA.w, o);
      accB.x += __shfl_xor(accB.x, o); accB.y += __shfl_xor(accB.y, o);
      accB.z += __shfl_xor(accB.z, o); accB.w += __shfl_xor(accB.w, o);
    }
    float inv = 1.f / (lrun + 1e-16f);
    float4 bA = *(const float4*)((const char*)bias + cb);
    float4 bB = *(const float4*)((const char*)bias + cb + 16);
    float4 oA, oB;
    oA.x = accA.x * inv + bA.x; oA.y = accA.y * inv + bA.y;
    oA.z = accA.z * inv + bA.z; oA.w = accA.w * inv + bA.w;
    oB.x = accB.x * inv + bB.x; oB.y = accB.y * inv + bB.y;
    oB.z = accB.z * inv + bB.z; oB.w = accB.w * inv + bB.w;
    if (do_elu){
      oA.x = oA.x > 0.f ? oA.x : (__expf(oA.x) - 1.f);
      oA.y = oA.y > 0.f ? oA.y : (__expf(oA.y) - 1.f);
      oA.z = oA.z > 0.f ? oA.z : (__expf(oA.z) - 1.f);
      oA.w = oA.w > 0.f ? oA.w : (__expf(oA.w) - 1.f);
      oB.x = oB.x > 0.f ? oB.x : (__expf(oB.x) - 1.f);
      oB.y = oB.y > 0.f ? oB.y : (__expf(oB.y) - 1.f);
      oB.z = oB.z > 0.f ? oB.z : (__expf(oB.z) - 1.f);
      oB.w = oB.w > 0.f ? oB.w : (__expf(oB.w) - 1.f);
    }
    if (outF){
      float4 wA = *(const float4*)((const char*)Wlin + cb);
      float4 wB = *(const float4*)((const char*)Wlin + cb + 16);
      float v = ((oA.x*wA.x + oA.y*wA.y) + (oA.z*wA.z + oA.w*wA.w))
              + ((oB.x*wB.x + oB.y*wB.y) + (oB.z*wB.z + oB.w*wB.w));
      #pragma unroll
      for (int o = 1; o < LPE; o <<= 1) v += __shfl_xor(v, o);
      if (lane == 0) outF[n] = v + blin[0];
    } else if (slot == 0){
      char* hb = (char*)hout + (((unsigned)n << SH) + cb);
      *(float4*)hb = oA;
      *(float4*)(hb + 16) = oB;
    }
  }
}

// ----------------------------------------------------------------
extern "C" void kernel_launch(void* const* d_in, const int* in_sizes, int n_in,
                              void* d_out, int out_size, void* d_ws, size_t ws_size,
                              hipStream_t stream)
{
  const float* x  = (const float*)d_in[0];
  const float* ea = (const float*)d_in[1];
  const int*   ei = (const int*)d_in[2];
  const int N = in_sizes[0] / 15;
  const int E = in_sizes[1];

  const float* P[28];
  for (int i = 0; i < 28; i++) P[i] = (const float*)d_in[3 + i];
  const float* Wlin = (const float*)d_in[31];
  const float* blin = (const float*)d_in[32];

  size_t off = 0;
  auto carve = [&](size_t bytes) -> char* {
    char* p = (char*)d_ws + off;
    off = (off + bytes + 255) & ~(size_t)255;
    return p;
  };
  int*   meta     = (int*)  carve(sizeof(int)  * (size_t)(3 * N + 64));
  int*   deg      = meta;                // [N] zeroed
  int*   pos      = meta + N;            // [N] zeroed
  int*   base     = meta + 2 * N;        // [N]
  int*   counter  = meta + 3 * N;        // [1] zeroed
  int2*  csr_pack = (int2*) carve(sizeof(int2) * (size_t)E);
  float* xl       = (float*)carve(sizeof(float) * (size_t)N * 128);
  float* xr       = (float*)carve(sizeof(float) * (size_t)N * 128);
  float* hA       = (float*)carve(sizeof(float) * (size_t)N * 128);
  float* hB       = (float*)carve(sizeof(float) * (size_t)N * 128);

  hipMemsetAsync(deg,     0, sizeof(int) * (size_t)(2 * N), stream);
  hipMemsetAsync(counter, 0, sizeof(int), stream);

  int eb = (E + 255) / 256;
  int nb = (N + 255) / 256;
  deg_count_kernel  <<<eb, 256, 0, stream>>>(ei + E, deg, E);
  base_assign_kernel<<<nb, 256, 0, stream>>>(deg, base, counter, N);
  fill_kernel       <<<eb, 256, 0, stream>>>(ei, ea, base, pos, csr_pack, E);

  // gemm grids: chunks = ceil(N/RPW); 4 waves (chunks) per block; grid.y = col-groups
  auto gemm_grid = [&](int rpw, int groups){
    int chunks = (N + rpw - 1) / rpw;
    return dim3((chunks + 3) / 4, groups);
  };
  int agrid = 2048;           // agg: grid-stride, 8 waves/block

  // layer 1: din=15, H*C=128, ELU
  gemm_cols_kernel<128, 15, 64><<<gemm_grid(64, 4), 256, 0, stream>>>(
      x, P[0], P[1], P[2], P[3], xl, xr, N);
  agg_kernel<16><<<agrid, 512, 0, stream>>>(xl, xr, base, deg, csr_pack, P[4], P[5], P[6], hA,
                                            nullptr, nullptr, nullptr, N, 1);
  // layer 2: din=128, ELU
  gemm_cols_kernel<128, 128, 64><<<gemm_grid(64, 4), 256, 0, stream>>>(
      hA, P[7], P[8], P[9], P[10], xl, xr, N);
  agg_kernel<16><<<agrid, 512, 0, stream>>>(xl, xr, base, deg, csr_pack, P[11], P[12], P[13], hB,
                                            nullptr, nullptr, nullptr, N, 1);
  // layer 3: din=128, ELU
  gemm_cols_kernel<128, 128, 64><<<gemm_grid(64, 4), 256, 0, stream>>>(
      hB, P[14], P[15], P[16], P[17], xl, xr, N);
  agg_kernel<16><<<agrid, 512, 0, stream>>>(xl, xr, base, deg, csr_pack, P[18], P[19], P[20], hA,
                                            nullptr, nullptr, nullptr, N, 1);
  // layer 4: din=128, H*C=64, no ELU + fused final linear 64->1
  gemm_cols_kernel<64, 128, 32><<<gemm_grid(32, 2), 256, 0, stream>>>(
      hA, P[21], P[22], P[23], P[24], xl, xr, N);
  agg_kernel<8><<<agrid, 512, 0, stream>>>(xl, xr, base, deg, csr_pack, P[25], P[26], P[27], hB,
                                           Wlin, blin, (float*)d_out, N, 0);
}